// Round 3
// baseline (635.272 us; speedup 1.0000x reference)
//
#include <hip/hip_runtime.h>
#include <hip/hip_cooperative_groups.h>
#include <cstdint>
#include <cstddef>

namespace cg = cooperative_groups;

#define BB 4
#define HQ 32
#define HKV 8
#define DD 128
#define S_PAST 8192
#define HID 4096
#define KVLEN 8193                 // S_PAST + 1
#define TOKEN_BUDGET 256
#define INIT_BUDGET 4
#define RECENT_BUDGET 256
#define ALLOW_LO INIT_BUDGET       // 4
#define ALLOW_HI (KVLEN - 1 - RECENT_BUDGET)  // 7936 inclusive
#define RECENT_LO (KVLEN - RECENT_BUDGET)     // 7937
#define SSTRIDE 8224

// ws layout in floats. Partials (OFF_P) alias the score region: qkv partials are
// dead before the score phase writes scores; out partials are written after the
// attn phase has consumed scores.
#define OFF_Q 0                       // [B][HQ*D]   = 16384
#define OFF_K 16384                   // [B][HKV*D]  = 4096
#define OFF_V 20480                   // [B][HKV*D]  = 4096
#define OFF_A 24576                   // [B][HQ*D]   = 16384
#define OFF_S 40960                   // [B][HQ][SSTRIDE] = 1052672
#define OFF_P 40960                   // aliases scores (see above)

#define NCH 128   // K-chunks for both GEMV phases (32 rows/chunk)

__device__ __forceinline__ unsigned fkey(float f) {
    unsigned u = __float_as_uint(f);
    return (u & 0x80000000u) ? ~u : (u | 0x80000000u); // monotone order-preserving map
}

// Wave-level suffix-select over 256 bucket counts. Lane t<64 holds 4 buckets.
__device__ __forceinline__ void suffix_select(const int* sbuf, int K,
                                              int* s_bucket, int* s_above, int* s_cntb,
                                              int tid) {
    if (tid < 64) {
        int4 h = ((const int4*)sbuf)[tid];
        int c = h.x + h.y + h.z + h.w;
        int x = c;
        #pragma unroll
        for (int off = 1; off < 64; off <<= 1) {
            int y = __shfl_down(x, off);
            if (tid + off < 64) x += y;
        }
        int excl = x - c;
        int s3 = excl + h.w;
        int s2 = s3 + h.z;
        int s1 = s2 + h.y;
        int s0 = s1 + h.x;
        if (s0 >= K && s1  < K) { *s_bucket = 4*tid+0; *s_above = s1;   *s_cntb = h.x; }
        if (s1 >= K && s2  < K) { *s_bucket = 4*tid+1; *s_above = s2;   *s_cntb = h.y; }
        if (s2 >= K && s3  < K) { *s_bucket = 4*tid+2; *s_above = s3;   *s_cntb = h.z; }
        if (s3 >= K && excl < K){ *s_bucket = 4*tid+3; *s_above = excl; *s_cntb = h.w; }
    }
}

// ---------------- Fused single cooperative kernel: 256 blocks x 512 threads ----------------
__global__ __launch_bounds__(512) void k_fused(
        const float* __restrict__ hidden, const float* __restrict__ cosp,
        const float* __restrict__ sinp,   const float* __restrict__ past_key,
        const float* __restrict__ past_value,
        const float* __restrict__ wq, const float* __restrict__ wk,
        const float* __restrict__ wv, const float* __restrict__ wo,
        float* __restrict__ out, float* __restrict__ ws, float* __restrict__ wsp) {
    cg::grid_group grid = cg::this_grid();
    const int tid = threadIdx.x;
    const int bid = blockIdx.x;           // 256 blocks
    const int sub = tid >> 8, t8 = tid & 255;

    // ---- shared memory (sum over phases ~73 KB < 160 KB) ----
    __shared__ float hs[BB][32];                       // qkv phase
    __shared__ float shr[2][2][BB][128];               // red phases, per-sub
    __shared__ float ao[2][BB][32];                    // out phase, per-sub
    __shared__ __align__(16) float rowl[8196];         // attn phase
    __shared__ __align__(16) int   hist[4096];
    __shared__ __align__(16) int   hist2[256];
    __shared__ int   wtot[4];
    __shared__ float redm[8];
    __shared__ int   s_bucket, s_above, s_cntb, s_cnt, s_done;
    __shared__ int   s_lo, s_hi, s_tc;
    __shared__ float s_sum;
    __shared__ int   list[520];
    __shared__ float wl[520];
    __shared__ __align__(16) float red[16][DD];

    // ================= Phase 1: fused QKV GEMV partials =================
    // 384 units: seg (2048 cols, 512 thr x float4) x 128 K-chunks (32 rows)
    for (int u = bid; u < 3 * NCH; u += 256) {
        const int seg = u >> 7, ch = u & 127;
        const int i0 = ch * 32;
        __syncthreads();
        if (tid < BB * 32) {
            int b = tid >> 5, ii = tid & 31;
            hs[b][ii] = hidden[b * HID + i0 + ii];
        }
        __syncthreads();
        const int c4 = seg * 2048 + tid * 4;
        const float* w; int stride; int local;
        if (c4 < 4096)      { w = wq; stride = HQ  * DD; local = c4;        }
        else if (c4 < 5120) { w = wk; stride = HKV * DD; local = c4 - 4096; }
        else                { w = wv; stride = HKV * DD; local = c4 - 5120; }
        const float* wp = w + (size_t)i0 * stride + local;
        float4 a0 = {0,0,0,0}, a1 = {0,0,0,0}, a2 = {0,0,0,0}, a3 = {0,0,0,0};
        for (int ii = 0; ii < 32; ii += 8) {
            float4 wr[8];
            #pragma unroll
            for (int uu = 0; uu < 8; ++uu)
                wr[uu] = *(const float4*)(wp + (size_t)(ii + uu) * stride);
            #pragma unroll
            for (int uu = 0; uu < 8; ++uu) {
                float h0 = hs[0][ii+uu], h1 = hs[1][ii+uu], h2 = hs[2][ii+uu], h3 = hs[3][ii+uu];
                float4 w4 = wr[uu];
                a0.x = fmaf(h0, w4.x, a0.x); a0.y = fmaf(h0, w4.y, a0.y); a0.z = fmaf(h0, w4.z, a0.z); a0.w = fmaf(h0, w4.w, a0.w);
                a1.x = fmaf(h1, w4.x, a1.x); a1.y = fmaf(h1, w4.y, a1.y); a1.z = fmaf(h1, w4.z, a1.z); a1.w = fmaf(h1, w4.w, a1.w);
                a2.x = fmaf(h2, w4.x, a2.x); a2.y = fmaf(h2, w4.y, a2.y); a2.z = fmaf(h2, w4.z, a2.z); a2.w = fmaf(h2, w4.w, a2.w);
                a3.x = fmaf(h3, w4.x, a3.x); a3.y = fmaf(h3, w4.y, a3.y); a3.z = fmaf(h3, w4.z, a3.z); a3.w = fmaf(h3, w4.w, a3.w);
            }
        }
        const int cq = seg * 512 + tid;
        ((float4*)(wsp + (size_t)(ch * 4 + 0) * 6144))[cq] = a0;
        ((float4*)(wsp + (size_t)(ch * 4 + 1) * 6144))[cq] = a1;
        ((float4*)(wsp + (size_t)(ch * 4 + 2) * 6144))[cq] = a2;
        ((float4*)(wsp + (size_t)(ch * 4 + 3) * 6144))[cq] = a3;
    }
    grid.sync();

    // ================= Phase 2: reduce qkv partials + fused RoPE =================
    // 48 units x 256 threads (2 subs/block, blocks 0..23)
    {
        const int unit = bid * 2 + sub;
        const int i = t8 & 127, half = t8 >> 7;
        const int c = unit * 128 + i;
        float s0 = 0.f, s1 = 0.f, s2 = 0.f, s3 = 0.f;
        if (unit < 48) {
            for (int cb = 0; cb < 64; cb += 8) {
                float r[8][4];
                #pragma unroll
                for (int uu = 0; uu < 8; ++uu) {
                    const float* p = wsp + (size_t)((half * 64 + cb + uu) * 4) * 6144 + c;
                    r[uu][0] = p[0]; r[uu][1] = p[6144]; r[uu][2] = p[2 * 6144]; r[uu][3] = p[3 * 6144];
                }
                #pragma unroll
                for (int uu = 0; uu < 8; ++uu) { s0 += r[uu][0]; s1 += r[uu][1]; s2 += r[uu][2]; s3 += r[uu][3]; }
            }
            shr[sub][half][0][i] = s0; shr[sub][half][1][i] = s1;
            shr[sub][half][2][i] = s2; shr[sub][half][3][i] = s3;
        }
        __syncthreads();
        if (unit < 48 && t8 < 128) {
            #pragma unroll
            for (int b = 0; b < BB; ++b) {
                float val  = shr[sub][0][b][i] + shr[sub][1][b][i];
                if (c < 5120) {  // rope on q and k_new
                    float part = shr[sub][0][b][i ^ 64] + shr[sub][1][b][i ^ 64];
                    float rot = (i < 64) ? -part : part;
                    val = fmaf(val, cosp[b * DD + i], rot * sinp[b * DD + i]);
                }
                float* dst;
                if (c < 4096)      dst = ws + OFF_Q + b * HQ * DD + c;
                else if (c < 5120) dst = ws + OFF_K + b * HKV * DD + (c - 4096);
                else               dst = ws + OFF_V + b * HKV * DD + (c - 5120);
                *dst = val;
            }
        }
    }
    grid.sync();

    // ================= Phase 3: scores =================
    // 1024 units x 256 threads: 2 subs/block x 2 passes
    for (int pass = 0; pass < 2; ++pass) {
        const int unit = bid * 2 + sub + pass * 512;
        const int chunk = unit & 31, bkv = unit >> 5;
        const int b = bkv >> 3, kv = bkv & 7;
        const int l = t8 & 31, g = t8 >> 5;
        const float scale = 0.08838834764831845f; // 1/sqrt(128)
        const float4* qbase = (const float4*)(ws + OFF_Q + ((size_t)b * HQ + kv * 4) * DD);
        float4 q0 = qbase[l], q1 = qbase[32 + l], q2 = qbase[64 + l], q3 = qbase[96 + l];
        q0.x *= scale; q0.y *= scale; q0.z *= scale; q0.w *= scale;
        q1.x *= scale; q1.y *= scale; q1.z *= scale; q1.w *= scale;
        q2.x *= scale; q2.y *= scale; q2.z *= scale; q2.w *= scale;
        q3.x *= scale; q3.y *= scale; q3.z *= scale; q3.w *= scale;
        const float* kbase = past_key + (size_t)(b * HKV + kv) * S_PAST * DD;
        const float4* knew = (const float4*)(ws + OFF_K + (b * HKV + kv) * DD);
        float* srow = ws + OFF_S + (size_t)(b * HQ + kv * 4) * SSTRIDE;
        const int base = chunk * 256;
        for (int rr = g; rr < 256; rr += 8) {
            float4 k4 = ((const float4*)(kbase + (size_t)(base + rr) * DD))[l];
            float p0 = k4.x*q0.x + k4.y*q0.y + k4.z*q0.z + k4.w*q0.w;
            float p1 = k4.x*q1.x + k4.y*q1.y + k4.z*q1.z + k4.w*q1.w;
            float p2 = k4.x*q2.x + k4.y*q2.y + k4.z*q2.z + k4.w*q2.w;
            float p3 = k4.x*q3.x + k4.y*q3.y + k4.z*q3.z + k4.w*q3.w;
            #pragma unroll
            for (int off = 16; off; off >>= 1) {
                p0 += __shfl_xor(p0, off); p1 += __shfl_xor(p1, off);
                p2 += __shfl_xor(p2, off); p3 += __shfl_xor(p3, off);
            }
            if (l == 0) {
                const int j = base + rr;
                srow[0 * SSTRIDE + j] = p0;
                srow[1 * SSTRIDE + j] = p1;
                srow[2 * SSTRIDE + j] = p2;
                srow[3 * SSTRIDE + j] = p3;
            }
        }
        if (chunk == 31 && g == 0) {   // tail row j = 8192 (k_new)
            float4 k4 = knew[l];
            float p0 = k4.x*q0.x + k4.y*q0.y + k4.z*q0.z + k4.w*q0.w;
            float p1 = k4.x*q1.x + k4.y*q1.y + k4.z*q1.z + k4.w*q1.w;
            float p2 = k4.x*q2.x + k4.y*q2.y + k4.z*q2.z + k4.w*q2.w;
            float p3 = k4.x*q3.x + k4.y*q3.y + k4.z*q3.z + k4.w*q3.w;
            #pragma unroll
            for (int off = 16; off; off >>= 1) {
                p0 += __shfl_xor(p0, off); p1 += __shfl_xor(p1, off);
                p2 += __shfl_xor(p2, off); p3 += __shfl_xor(p3, off);
            }
            if (l == 0) {
                srow[0 * SSTRIDE + 8192] = p0; srow[1 * SSTRIDE + 8192] = p1;
                srow[2 * SSTRIDE + 8192] = p2; srow[3 * SSTRIDE + 8192] = p3;
            }
        }
    }
    grid.sync();

    // ================= Phase 4: per-(b,h) top-k + softmax + A@V =================
    if (bid < BB * HQ) {
        const int blk = bid;
        const int b = blk >> 5, h = blk & 31, kv = h >> 2;
        const float* srow = ws + OFF_S + (size_t)(b * HQ + h) * SSTRIDE;

        for (int i = tid; i < 4096; i += 512) hist[i] = 0;
        if (tid == 0) { s_cnt = 0; s_sum = 0.f; }
        __syncthreads();

        // ---- single pass: row -> LDS (float4) + max + 4096-bin histogram ----
        float m = -3.4e38f;
        for (int i4 = tid; i4 < 2048; i4 += 512) {
            float4 v = ((const float4*)srow)[i4];
            ((float4*)rowl)[i4] = v;
            m = fmaxf(fmaxf(m, fmaxf(v.x, v.y)), fmaxf(v.z, v.w));
            if (i4 >= 1 && i4 <= 1983) {          // j = 4*i4.. fully inside [4,7936]
                atomicAdd(&hist[fkey(v.x) >> 20], 1);
                atomicAdd(&hist[fkey(v.y) >> 20], 1);
                atomicAdd(&hist[fkey(v.z) >> 20], 1);
                atomicAdd(&hist[fkey(v.w) >> 20], 1);
            } else {
                int j = i4 * 4;
                if (j+0 >= ALLOW_LO && j+0 <= ALLOW_HI) atomicAdd(&hist[fkey(v.x) >> 20], 1);
                if (j+1 >= ALLOW_LO && j+1 <= ALLOW_HI) atomicAdd(&hist[fkey(v.y) >> 20], 1);
                if (j+2 >= ALLOW_LO && j+2 <= ALLOW_HI) atomicAdd(&hist[fkey(v.z) >> 20], 1);
                if (j+3 >= ALLOW_LO && j+3 <= ALLOW_HI) atomicAdd(&hist[fkey(v.w) >> 20], 1);
            }
        }
        if (tid == 0) { float s = srow[8192]; rowl[8192] = s; m = fmaxf(m, s); }
        #pragma unroll
        for (int off = 32; off; off >>= 1) m = fmaxf(m, __shfl_xor(m, off));
        if ((tid & 63) == 0) redm[tid >> 6] = m;
        __syncthreads();
        m = fmaxf(fmaxf(fmaxf(redm[0], redm[1]), fmaxf(redm[2], redm[3])),
                  fmaxf(fmaxf(redm[4], redm[5]), fmaxf(redm[6], redm[7])));

        // ---- hierarchical suffix-select: first 256 threads own 16 bins each ----
        const int lane = tid & 63;
        int hc[16]; int csum = 0;
        if (tid < 256) {
            #pragma unroll
            for (int q = 0; q < 4; ++q) {
                int4 v = ((const int4*)hist)[tid * 4 + q];
                hc[4*q] = v.x; hc[4*q+1] = v.y; hc[4*q+2] = v.z; hc[4*q+3] = v.w;
                csum += v.x + v.y + v.z + v.w;
            }
        }
        int x = csum;
        #pragma unroll
        for (int off = 1; off < 64; off <<= 1) {
            int y = __shfl_down(x, off);
            if (lane + off < 64) x += y;
        }
        if (tid < 256 && lane == 0) wtot[tid >> 6] = x;
        __syncthreads();
        if (tid < 256) {
            const int w = tid >> 6;
            int high = 0;
            for (int w2 = w + 1; w2 < 4; ++w2) high += wtot[w2];
            int run = (x - csum) + high;   // count strictly above this thread's chunks
            #pragma unroll
            for (int i = 15; i >= 0; --i) {
                int inc = run + hc[i];
                if (inc >= TOKEN_BUDGET && run < TOKEN_BUDGET) {
                    s_bucket = 16 * tid + i; s_above = run; s_cntb = hc[i];
                }
                run = inc;
            }
        }
        __syncthreads();

        int Kc = TOKEN_BUDGET - s_above;
        int E  = s_cntb;
        unsigned pref = (unsigned)s_bucket;    // 12 bits
        unsigned tkey = pref << 20;
        int jcut = ALLOW_HI;
        if (tid == 0) s_done = (E == Kc);
        __syncthreads();

        // ---- refine level 2: bits [19:12] ----
        if (!s_done) {
            if (tid < 256) hist2[tid] = 0;
            __syncthreads();
            for (int j = ALLOW_LO + tid; j <= ALLOW_HI; j += 512) {
                unsigned u = fkey(rowl[j]);
                if ((u >> 20) == pref) atomicAdd(&hist2[(u >> 12) & 255], 1);
            }
            __syncthreads();
            suffix_select(hist2, Kc, &s_bucket, &s_above, &s_cntb, tid);
            __syncthreads();
            Kc -= s_above; E = s_cntb;
            pref = (pref << 8) | (unsigned)s_bucket;   // 20 bits
            tkey = pref << 12;
            if (tid == 0) s_done = (E == Kc);
            __syncthreads();
        }
        // ---- refine level 3: bits [11:4] ----
        if (!s_done) {
            if (tid < 256) hist2[tid] = 0;
            __syncthreads();
            for (int j = ALLOW_LO + tid; j <= ALLOW_HI; j += 512) {
                unsigned u = fkey(rowl[j]);
                if ((u >> 12) == pref) atomicAdd(&hist2[(u >> 4) & 255], 1);
            }
            __syncthreads();
            suffix_select(hist2, Kc, &s_bucket, &s_above, &s_cntb, tid);
            __syncthreads();
            Kc -= s_above; E = s_cntb;
            pref = (pref << 8) | (unsigned)s_bucket;   // 28 bits
            tkey = pref << 4;
            if (tid == 0) s_done = (E == Kc);
            __syncthreads();
        }
        // ---- refine level 4: bits [3:0] (exact key) ----
        if (!s_done) {
            if (tid < 256) hist2[tid] = 0;
            __syncthreads();
            for (int j = ALLOW_LO + tid; j <= ALLOW_HI; j += 512) {
                unsigned u = fkey(rowl[j]);
                if ((u >> 4) == pref) atomicAdd(&hist2[u & 15], 1);
            }
            __syncthreads();
            suffix_select(hist2, Kc, &s_bucket, &s_above, &s_cntb, tid);
            __syncthreads();
            Kc -= s_above; E = s_cntb;
            tkey = (pref << 4) | (unsigned)s_bucket;   // exact key of K-th largest
            if (E > Kc) {   // exact ties: smallest jcut with count(key==tkey, j<=jcut) >= Kc
                if (tid == 0) { s_lo = ALLOW_LO; s_hi = ALLOW_HI; }
                __syncthreads();
                while (s_lo < s_hi) {
                    int mid = (s_lo + s_hi) >> 1;
                    if (tid == 0) s_tc = 0;
                    __syncthreads();
                    int loc = 0;
                    for (int j = ALLOW_LO + tid; j <= mid; j += 512)
                        if (fkey(rowl[j]) == tkey) loc++;
                    if (loc) atomicAdd(&s_tc, loc);
                    __syncthreads();
                    if (tid == 0) { if (s_tc >= Kc) s_hi = mid; else s_lo = mid + 1; }
                    __syncthreads();
                }
                jcut = s_lo;
            }
            __syncthreads();
        }

        // ---- compact kept set (ballot) + softmax weights ----
        float lsum = 0.f;
        for (int j = tid; j < KVLEN; j += 512) {
            float s = rowl[j];
            bool keep;
            if (j < INIT_BUDGET || j >= RECENT_LO) keep = true;
            else {
                unsigned u = fkey(s);
                keep = (u > tkey) || (u == tkey && j <= jcut);
            }
            unsigned long long mask = __ballot(keep);
            if (mask) {
                int leader = (int)__ffsll((unsigned long long)mask) - 1;
                int cw = __popcll(mask);
                int base2 = 0;
                if (lane == leader) base2 = atomicAdd(&s_cnt, cw);
                base2 = __shfl(base2, leader);
                if (keep) {
                    int p = base2 + __popcll(mask & ((1ull << lane) - 1ull));
                    float e = __expf(s - m);
                    list[p] = j; wl[p] = e;
                    lsum += e;
                }
            }
        }
        #pragma unroll
        for (int off = 32; off; off >>= 1) lsum += __shfl_xor(lsum, off);
        if (lane == 0) atomicAdd(&s_sum, lsum);
        __syncthreads();
        const int cnt = s_cnt;           // = 516
        const float inv = 1.0f / s_sum;

        // ---- gathered A@V: 16 groups x 32 lanes, 8 rows in flight ----
        const int G = tid >> 5, dq = tid & 31;
        const float4* vnew = (const float4*)(ws + OFF_V + (b * HKV + kv) * DD);
        const float* vbase = past_value + (size_t)(b * HKV + kv) * S_PAST * DD;
        float4 acc = {0.f, 0.f, 0.f, 0.f};
        for (int e = G; e < cnt; e += 128) {
            int jj[8]; float wv8[8]; float4 v4[8];
            #pragma unroll
            for (int k = 0; k < 8; ++k) {
                int ee = e + 16 * k;
                bool ok = ee < cnt;
                jj[k]  = ok ? list[ee] : 0;
                wv8[k] = ok ? wl[ee]   : 0.f;
            }
            #pragma unroll
            for (int k = 0; k < 8; ++k) {
                int j = jj[k];
                v4[k] = (j < S_PAST) ? ((const float4*)(vbase + (size_t)j * DD))[dq] : vnew[dq];
            }
            #pragma unroll
            for (int k = 0; k < 8; ++k) {
                acc.x = fmaf(wv8[k], v4[k].x, acc.x);
                acc.y = fmaf(wv8[k], v4[k].y, acc.y);
                acc.z = fmaf(wv8[k], v4[k].z, acc.z);
                acc.w = fmaf(wv8[k], v4[k].w, acc.w);
            }
        }
        red[G][dq * 4 + 0] = acc.x; red[G][dq * 4 + 1] = acc.y;
        red[G][dq * 4 + 2] = acc.z; red[G][dq * 4 + 3] = acc.w;
        __syncthreads();
        if (tid < DD) {
            float s = 0.f;
            #pragma unroll
            for (int gg = 0; gg < 16; ++gg) s += red[gg][tid];
            ws[OFF_A + b * HQ * DD + h * DD + tid] = s * inv;
        }
    }
    grid.sync();

    // ================= Phase 5: output GEMV partials =================
    // 512 units x 256 threads: 2 subs/block, exactly 1 pass
    {
        const int unit = bid * 2 + sub;   // 0..511
        const int bx = unit >> 7, ch = unit & 127;
        const int i0 = ch * 32;
        if (t8 < BB * 32) {
            int b = t8 >> 5, ii = t8 & 31;
            ao[sub][b][ii] = ws[OFF_A + b * HQ * DD + i0 + ii];
        }
        __syncthreads();
        const int c4 = bx * 1024 + t8 * 4;
        const float* wp = wo + (size_t)i0 * HID + c4;
        float4 a0 = {0,0,0,0}, a1 = {0,0,0,0}, a2 = {0,0,0,0}, a3 = {0,0,0,0};
        for (int ii = 0; ii < 32; ii += 8) {
            float4 wr[8];
            #pragma unroll
            for (int uu = 0; uu < 8; ++uu)
                wr[uu] = *(const float4*)(wp + (size_t)(ii + uu) * HID);
            #pragma unroll
            for (int uu = 0; uu < 8; ++uu) {
                float h0 = ao[sub][0][ii+uu], h1 = ao[sub][1][ii+uu];
                float h2 = ao[sub][2][ii+uu], h3 = ao[sub][3][ii+uu];
                float4 w4 = wr[uu];
                a0.x = fmaf(h0, w4.x, a0.x); a0.y = fmaf(h0, w4.y, a0.y); a0.z = fmaf(h0, w4.z, a0.z); a0.w = fmaf(h0, w4.w, a0.w);
                a1.x = fmaf(h1, w4.x, a1.x); a1.y = fmaf(h1, w4.y, a1.y); a1.z = fmaf(h1, w4.z, a1.z); a1.w = fmaf(h1, w4.w, a1.w);
                a2.x = fmaf(h2, w4.x, a2.x); a2.y = fmaf(h2, w4.y, a2.y); a2.z = fmaf(h2, w4.z, a2.z); a2.w = fmaf(h2, w4.w, a2.w);
                a3.x = fmaf(h3, w4.x, a3.x); a3.y = fmaf(h3, w4.y, a3.y); a3.z = fmaf(h3, w4.z, a3.z); a3.w = fmaf(h3, w4.w, a3.w);
            }
        }
        const int cq = bx * 256 + t8;
        ((float4*)(wsp + (size_t)(ch * 4 + 0) * HID))[cq] = a0;
        ((float4*)(wsp + (size_t)(ch * 4 + 1) * HID))[cq] = a1;
        ((float4*)(wsp + (size_t)(ch * 4 + 2) * HID))[cq] = a2;
        ((float4*)(wsp + (size_t)(ch * 4 + 3) * HID))[cq] = a3;
    }
    grid.sync();

    // ================= Phase 6: reduce out partials -> d_out =================
    // 32 units x 256 threads: 2 subs/block, blocks 0..15
    {
        const int unit = bid * 2 + sub;
        const int i = t8 & 127, half = t8 >> 7;
        const int c = unit * 128 + i;
        if (unit < 32) {
            float s0 = 0.f, s1 = 0.f, s2 = 0.f, s3 = 0.f;
            for (int cb = 0; cb < 64; cb += 8) {
                float r[8][4];
                #pragma unroll
                for (int uu = 0; uu < 8; ++uu) {
                    const float* p = wsp + (size_t)((half * 64 + cb + uu) * 4) * HID + c;
                    r[uu][0] = p[0]; r[uu][1] = p[HID]; r[uu][2] = p[2 * HID]; r[uu][3] = p[3 * HID];
                }
                #pragma unroll
                for (int uu = 0; uu < 8; ++uu) { s0 += r[uu][0]; s1 += r[uu][1]; s2 += r[uu][2]; s3 += r[uu][3]; }
            }
            shr[sub][half][0][i] = s0; shr[sub][half][1][i] = s1;
            shr[sub][half][2][i] = s2; shr[sub][half][3][i] = s3;
        }
        __syncthreads();
        if (unit < 32 && t8 < 128) {
            #pragma unroll
            for (int b = 0; b < BB; ++b)
                out[b * HID + c] = shr[sub][0][b][i] + shr[sub][1][b][i];
        }
    }
}

extern "C" void kernel_launch(void* const* d_in, const int* in_sizes, int n_in,
                              void* d_out, int out_size, void* d_ws, size_t ws_size,
                              hipStream_t stream) {
    const float* hidden = (const float*)d_in[0];
    const float* cosp   = (const float*)d_in[1];
    const float* sinp   = (const float*)d_in[2];
    const float* pk     = (const float*)d_in[3];
    const float* pv     = (const float*)d_in[4];
    const float* wq     = (const float*)d_in[5];
    const float* wk     = (const float*)d_in[6];
    const float* wv     = (const float*)d_in[7];
    const float* wo     = (const float*)d_in[8];
    float* out = (float*)d_out;
    float* ws  = (float*)d_ws;
    float* wsp = ws + OFF_P;

    void* args[] = { (void*)&hidden, (void*)&cosp, (void*)&sinp, (void*)&pk, (void*)&pv,
                     (void*)&wq, (void*)&wk, (void*)&wv, (void*)&wo,
                     (void*)&out, (void*)&ws, (void*)&wsp };
    hipLaunchCooperativeKernel((void*)k_fused, dim3(256), dim3(512), args, 0, stream);
}

// Round 5
// 426.798 us; speedup vs baseline: 1.4885x; 1.4885x over previous
//
#include <hip/hip_runtime.h>
#include <cstdint>
#include <cstddef>

#define BB 4
#define HQ 32
#define HKV 8
#define DD 128
#define S_PAST 8192
#define HID 4096
#define KVLEN 8193                 // S_PAST + 1
#define TOKEN_BUDGET 256
#define INIT_BUDGET 4
#define RECENT_BUDGET 256
#define ALLOW_LO INIT_BUDGET       // 4
#define ALLOW_HI (KVLEN - 1 - RECENT_BUDGET)  // 7936 inclusive
#define RECENT_LO (KVLEN - RECENT_BUDGET)     // 7937
#define SSTRIDE 8224

// ws layout in floats. Partials (OFF_P) alias the score region: qkv partials are
// dead before k_scores writes scores; out partials are written after k_attn has
// consumed scores.
#define OFF_Q 0                       // [B][HQ*D]   = 16384
#define OFF_K 16384                   // [B][HKV*D]  = 4096
#define OFF_V 20480                   // [B][HKV*D]  = 4096
#define OFF_A 24576                   // [B][HQ*D]   = 16384
#define OFF_S 40960                   // [B][HQ][SSTRIDE] = 1052672
#define OFF_P 40960                   // aliases scores (see above)

#define NCH1 128  // K-chunks for qkv GEMV (32 rows/chunk)
#define NCH2 128  // K-chunks for out GEMV (32 rows/chunk)

__device__ __forceinline__ unsigned fkey(float f) {
    unsigned u = __float_as_uint(f);
    return (u & 0x80000000u) ? ~u : (u | 0x80000000u); // monotone order-preserving map
}

typedef float vfloat4 __attribute__((ext_vector_type(4)));

__device__ __forceinline__ float4 ntload4(const float4* p) {
    vfloat4 v = __builtin_nontemporal_load((const vfloat4*)p);
    return make_float4(v.x, v.y, v.z, v.w);
}

// ---------------- Kernel 1: fused QKV GEMV, 8-deep float4 pipeline ----------------
__global__ __launch_bounds__(256) void k_qkv(const float* __restrict__ hidden,
                                             const float* __restrict__ wq,
                                             const float* __restrict__ wk,
                                             const float* __restrict__ wv,
                                             float* __restrict__ wsp) {
    __shared__ float hs[BB][32];
    const int tid = threadIdx.x;
    const int bx = blockIdx.x, ch = blockIdx.y;
    const int i0 = ch * 32;
    if (tid < BB * 32) {
        int b = tid >> 5, ii = tid & 31;
        hs[b][ii] = hidden[b * HID + i0 + ii];
    }
    __syncthreads();
    const int c4 = bx * 1024 + tid * 4;
    const float* w; int stride; int local;
    if (bx < 4)       { w = wq; stride = HQ  * DD; local = c4;        }
    else if (bx == 4) { w = wk; stride = HKV * DD; local = c4 - 4096; }
    else              { w = wv; stride = HKV * DD; local = c4 - 5120; }
    const float* wp = w + (size_t)i0 * stride + local;
    float4 a0 = {0,0,0,0}, a1 = {0,0,0,0}, a2 = {0,0,0,0}, a3 = {0,0,0,0};
    for (int ii = 0; ii < 32; ii += 8) {
        float4 wr[8];
        #pragma unroll
        for (int u = 0; u < 8; ++u)
            wr[u] = ntload4((const float4*)(wp + (size_t)(ii + u) * stride));
        #pragma unroll
        for (int u = 0; u < 8; ++u) {
            float h0 = hs[0][ii+u], h1 = hs[1][ii+u], h2 = hs[2][ii+u], h3 = hs[3][ii+u];
            float4 w4 = wr[u];
            a0.x = fmaf(h0, w4.x, a0.x); a0.y = fmaf(h0, w4.y, a0.y); a0.z = fmaf(h0, w4.z, a0.z); a0.w = fmaf(h0, w4.w, a0.w);
            a1.x = fmaf(h1, w4.x, a1.x); a1.y = fmaf(h1, w4.y, a1.y); a1.z = fmaf(h1, w4.z, a1.z); a1.w = fmaf(h1, w4.w, a1.w);
            a2.x = fmaf(h2, w4.x, a2.x); a2.y = fmaf(h2, w4.y, a2.y); a2.z = fmaf(h2, w4.z, a2.z); a2.w = fmaf(h2, w4.w, a2.w);
            a3.x = fmaf(h3, w4.x, a3.x); a3.y = fmaf(h3, w4.y, a3.y); a3.z = fmaf(h3, w4.z, a3.z); a3.w = fmaf(h3, w4.w, a3.w);
        }
    }
    const int cq = bx * 256 + tid;
    ((float4*)(wsp + (size_t)(ch * 4 + 0) * 6144))[cq] = a0;
    ((float4*)(wsp + (size_t)(ch * 4 + 1) * 6144))[cq] = a1;
    ((float4*)(wsp + (size_t)(ch * 4 + 2) * 6144))[cq] = a2;
    ((float4*)(wsp + (size_t)(ch * 4 + 3) * 6144))[cq] = a3;
}

// ---------------- Kernel 2: reduce qkv partials + fused RoPE ----------------
__global__ __launch_bounds__(256) void k_qkv_red(const float* __restrict__ wsp,
                                                 const float* __restrict__ cosp,
                                                 const float* __restrict__ sinp,
                                                 float* __restrict__ ws) {
    __shared__ float sh[2][BB][128];
    const int tid = threadIdx.x;
    const int i = tid & 127, half = tid >> 7;
    const int c = blockIdx.x * 128 + i;
    float s0 = 0.f, s1 = 0.f, s2 = 0.f, s3 = 0.f;
    for (int cb = 0; cb < 64; cb += 8) {
        float r[8][4];
        #pragma unroll
        for (int u = 0; u < 8; ++u) {
            const float* p = wsp + (size_t)((half * 64 + cb + u) * 4) * 6144 + c;
            r[u][0] = p[0]; r[u][1] = p[6144]; r[u][2] = p[2 * 6144]; r[u][3] = p[3 * 6144];
        }
        #pragma unroll
        for (int u = 0; u < 8; ++u) { s0 += r[u][0]; s1 += r[u][1]; s2 += r[u][2]; s3 += r[u][3]; }
    }
    sh[half][0][i] = s0; sh[half][1][i] = s1; sh[half][2][i] = s2; sh[half][3][i] = s3;
    __syncthreads();
    if (tid < 128) {
        #pragma unroll
        for (int b = 0; b < BB; ++b) {
            float val  = sh[0][b][i] + sh[1][b][i];
            if (c < 5120) {  // rope on q and k_new
                float part = sh[0][b][i ^ 64] + sh[1][b][i ^ 64];
                float rot = (i < 64) ? -part : part;
                val = fmaf(val, cosp[b * DD + i], rot * sinp[b * DD + i]);
            }
            float* dst;
            if (c < 4096)      dst = ws + OFF_Q + b * HQ * DD + c;
            else if (c < 5120) dst = ws + OFF_K + b * HKV * DD + (c - 4096);
            else               dst = ws + OFF_V + b * HKV * DD + (c - 5120);
            *dst = val;
        }
    }
}

// ---------------- Kernel 3: scores; 32 lanes per K-row, 8 rows in flight ----------------
__global__ __launch_bounds__(256) void k_scores(const float* __restrict__ past_key,
                                                float* __restrict__ ws) {
    const int tid = threadIdx.x, blk = blockIdx.x;
    const int chunk = blk & 31, bkv = blk >> 5;
    const int b = bkv >> 3, kv = bkv & 7;
    const int l = tid & 31, g = tid >> 5;   // 8 groups of 32 lanes
    const float scale = 0.08838834764831845f; // 1/sqrt(128)
    const float4* qbase = (const float4*)(ws + OFF_Q + ((size_t)b * HQ + kv * 4) * DD);
    float4 q0 = qbase[l], q1 = qbase[32 + l], q2 = qbase[64 + l], q3 = qbase[96 + l];
    q0.x *= scale; q0.y *= scale; q0.z *= scale; q0.w *= scale;
    q1.x *= scale; q1.y *= scale; q1.z *= scale; q1.w *= scale;
    q2.x *= scale; q2.y *= scale; q2.z *= scale; q2.w *= scale;
    q3.x *= scale; q3.y *= scale; q3.z *= scale; q3.w *= scale;
    const float* kbase = past_key + (size_t)(b * HKV + kv) * S_PAST * DD;
    const float4* knew = (const float4*)(ws + OFF_K + (b * HKV + kv) * DD);
    float* srow = ws + OFF_S + (size_t)(b * HQ + kv * 4) * SSTRIDE;
    const int base = chunk * 256;
    // rows: j = base + g + 8*(8*it + t), it<4, t<8 — 8 independent loads in flight
    for (int it = 0; it < 4; ++it) {
        float4 k4[8];
        #pragma unroll
        for (int t = 0; t < 8; ++t) {
            const int row = base + g + 8 * (8 * it + t);
            k4[t] = ntload4(((const float4*)(kbase + (size_t)row * DD)) + l);
        }
        float p[8][4];
        #pragma unroll
        for (int t = 0; t < 8; ++t) {
            p[t][0] = k4[t].x*q0.x + k4[t].y*q0.y + k4[t].z*q0.z + k4[t].w*q0.w;
            p[t][1] = k4[t].x*q1.x + k4[t].y*q1.y + k4[t].z*q1.z + k4[t].w*q1.w;
            p[t][2] = k4[t].x*q2.x + k4[t].y*q2.y + k4[t].z*q2.z + k4[t].w*q2.w;
            p[t][3] = k4[t].x*q3.x + k4[t].y*q3.y + k4[t].z*q3.z + k4[t].w*q3.w;
        }
        #pragma unroll
        for (int off = 16; off; off >>= 1) {
            #pragma unroll
            for (int t = 0; t < 8; ++t) {
                p[t][0] += __shfl_xor(p[t][0], off);
                p[t][1] += __shfl_xor(p[t][1], off);
                p[t][2] += __shfl_xor(p[t][2], off);
                p[t][3] += __shfl_xor(p[t][3], off);
            }
        }
        // all 32 lanes hold all 32 reduced values; lane l stores (t=l>>2, h=l&3)
        float v = p[0][0];
        #pragma unroll
        for (int t = 0; t < 8; ++t)
            #pragma unroll
            for (int h2 = 0; h2 < 4; ++h2)
                if ((l >> 2) == t && (l & 3) == h2) v = p[t][h2];
        srow[(size_t)(l & 3) * SSTRIDE + base + g + 8 * (8 * it + (l >> 2))] = v;
    }
    if (chunk == 31 && g == 0) {   // tail row j = 8192 (k_new)
        float4 k4 = knew[l];
        float p0 = k4.x*q0.x + k4.y*q0.y + k4.z*q0.z + k4.w*q0.w;
        float p1 = k4.x*q1.x + k4.y*q1.y + k4.z*q1.z + k4.w*q1.w;
        float p2 = k4.x*q2.x + k4.y*q2.y + k4.z*q2.z + k4.w*q2.w;
        float p3 = k4.x*q3.x + k4.y*q3.y + k4.z*q3.z + k4.w*q3.w;
        #pragma unroll
        for (int off = 16; off; off >>= 1) {
            p0 += __shfl_xor(p0, off); p1 += __shfl_xor(p1, off);
            p2 += __shfl_xor(p2, off); p3 += __shfl_xor(p3, off);
        }
        float pv = p0;
        pv = (l == 1) ? p1 : pv;
        pv = (l == 2) ? p2 : pv;
        pv = (l == 3) ? p3 : pv;
        if (l < 4) srow[(size_t)l * SSTRIDE + 8192] = pv;
    }
}

// Wave-level suffix-select over 256 bucket counts. Lane t<64 holds 4 buckets.
__device__ __forceinline__ void suffix_select(const int* sbuf, int K,
                                              int* s_bucket, int* s_above, int* s_cntb,
                                              int tid) {
    if (tid < 64) {
        int4 h = ((const int4*)sbuf)[tid];
        int c = h.x + h.y + h.z + h.w;
        int x = c;
        #pragma unroll
        for (int off = 1; off < 64; off <<= 1) {
            int y = __shfl_down(x, off);
            if (tid + off < 64) x += y;
        }
        int excl = x - c;
        int s3 = excl + h.w;
        int s2 = s3 + h.z;
        int s1 = s2 + h.y;
        int s0 = s1 + h.x;
        if (s0 >= K && s1  < K) { *s_bucket = 4*tid+0; *s_above = s1;   *s_cntb = h.x; }
        if (s1 >= K && s2  < K) { *s_bucket = 4*tid+1; *s_above = s2;   *s_cntb = h.y; }
        if (s2 >= K && s3  < K) { *s_bucket = 4*tid+2; *s_above = s3;   *s_cntb = h.z; }
        if (s3 >= K && excl < K){ *s_bucket = 4*tid+3; *s_above = excl; *s_cntb = h.w; }
    }
}

// ---------------- Kernel 4: per-(b,h) top-k + softmax + A@V, LDS-resident row ----------------
__global__ __launch_bounds__(1024) void k_attn(const float* __restrict__ past_value,
                                               float* __restrict__ ws) {
    const int tid = threadIdx.x;
    const int blk = blockIdx.x;          // B*HQ = 128
    const int b = blk >> 5, h = blk & 31, kv = h >> 2;
    const float* srow = ws + OFF_S + (size_t)(b * HQ + h) * SSTRIDE;

    __shared__ __align__(16) float rowl[8196];
    __shared__ __align__(16) int   hist[4096];
    __shared__ __align__(16) int   hist2[256];
    __shared__ int   wtot[4];
    __shared__ float redm[16];
    __shared__ int   s_bucket, s_above, s_cntb, s_cnt, s_done;
    __shared__ int   s_lo, s_hi, s_tc;
    __shared__ float s_sum;
    __shared__ int   list[520];
    __shared__ float wl[520];
    __shared__ __align__(16) float red[32][DD];

    for (int i = tid; i < 4096; i += 1024) hist[i] = 0;
    if (tid == 0) { s_cnt = 0; s_sum = 0.f; }
    __syncthreads();

    // ---- single pass: row -> LDS (float4) + max + 4096-bin histogram (top 12 bits) ----
    float m = -3.4e38f;
    for (int i4 = tid; i4 < 2048; i4 += 1024) {
        float4 v = ((const float4*)srow)[i4];
        ((float4*)rowl)[i4] = v;
        m = fmaxf(fmaxf(m, fmaxf(v.x, v.y)), fmaxf(v.z, v.w));
        if (i4 >= 1 && i4 <= 1983) {          // j = 4*i4.. fully inside [4,7936]
            atomicAdd(&hist[fkey(v.x) >> 20], 1);
            atomicAdd(&hist[fkey(v.y) >> 20], 1);
            atomicAdd(&hist[fkey(v.z) >> 20], 1);
            atomicAdd(&hist[fkey(v.w) >> 20], 1);
        } else {
            int j = i4 * 4;
            if (j+0 >= ALLOW_LO && j+0 <= ALLOW_HI) atomicAdd(&hist[fkey(v.x) >> 20], 1);
            if (j+1 >= ALLOW_LO && j+1 <= ALLOW_HI) atomicAdd(&hist[fkey(v.y) >> 20], 1);
            if (j+2 >= ALLOW_LO && j+2 <= ALLOW_HI) atomicAdd(&hist[fkey(v.z) >> 20], 1);
            if (j+3 >= ALLOW_LO && j+3 <= ALLOW_HI) atomicAdd(&hist[fkey(v.w) >> 20], 1);
        }
    }
    if (tid == 0) { float s = srow[8192]; rowl[8192] = s; m = fmaxf(m, s); }
    #pragma unroll
    for (int off = 32; off; off >>= 1) m = fmaxf(m, __shfl_xor(m, off));
    if ((tid & 63) == 0) redm[tid >> 6] = m;
    __syncthreads();
    m = redm[0];
    #pragma unroll
    for (int q = 1; q < 16; ++q) m = fmaxf(m, redm[q]);

    // ---- hierarchical suffix-select over 4096 bins: first 256 threads own 16 bins ----
    const int lane = tid & 63;
    int hc[16]; int csum = 0;
    if (tid < 256) {
        #pragma unroll
        for (int q = 0; q < 4; ++q) {
            int4 v = ((const int4*)hist)[tid * 4 + q];
            hc[4*q] = v.x; hc[4*q+1] = v.y; hc[4*q+2] = v.z; hc[4*q+3] = v.w;
            csum += v.x + v.y + v.z + v.w;
        }
    }
    int x = csum;
    #pragma unroll
    for (int off = 1; off < 64; off <<= 1) {
        int y = __shfl_down(x, off);
        if (lane + off < 64) x += y;
    }
    if (tid < 256 && lane == 0) wtot[tid >> 6] = x;
    __syncthreads();
    if (tid < 256) {
        const int w = tid >> 6;
        int high = 0;
        for (int w2 = w + 1; w2 < 4; ++w2) high += wtot[w2];
        int run = (x - csum) + high;       // count in chunks strictly above this thread's
        #pragma unroll
        for (int i = 15; i >= 0; --i) {
            int inc = run + hc[i];
            if (inc >= TOKEN_BUDGET && run < TOKEN_BUDGET) {
                s_bucket = 16 * tid + i; s_above = run; s_cntb = hc[i];
            }
            run = inc;
        }
    }
    __syncthreads();

    int Kc = TOKEN_BUDGET - s_above;
    int E  = s_cntb;
    unsigned pref = (unsigned)s_bucket;    // 12 bits
    unsigned tkey = pref << 20;
    int jcut = ALLOW_HI;
    if (tid == 0) s_done = (E == Kc);
    __syncthreads();

    // ---- refine level 2: bits [19:12] ----
    if (!s_done) {
        if (tid < 256) hist2[tid] = 0;
        __syncthreads();
        for (int j = ALLOW_LO + tid; j <= ALLOW_HI; j += 1024) {
            unsigned u = fkey(rowl[j]);
            if ((u >> 20) == pref) atomicAdd(&hist2[(u >> 12) & 255], 1);
        }
        __syncthreads();
        suffix_select(hist2, Kc, &s_bucket, &s_above, &s_cntb, tid);
        __syncthreads();
        Kc -= s_above; E = s_cntb;
        pref = (pref << 8) | (unsigned)s_bucket;   // 20 bits
        tkey = pref << 12;
        if (tid == 0) s_done = (E == Kc);
        __syncthreads();
    }
    // ---- refine level 3: bits [11:4] ----
    if (!s_done) {
        if (tid < 256) hist2[tid] = 0;
        __syncthreads();
        for (int j = ALLOW_LO + tid; j <= ALLOW_HI; j += 1024) {
            unsigned u = fkey(rowl[j]);
            if ((u >> 12) == pref) atomicAdd(&hist2[(u >> 4) & 255], 1);
        }
        __syncthreads();
        suffix_select(hist2, Kc, &s_bucket, &s_above, &s_cntb, tid);
        __syncthreads();
        Kc -= s_above; E = s_cntb;
        pref = (pref << 8) | (unsigned)s_bucket;   // 28 bits
        tkey = pref << 4;
        if (tid == 0) s_done = (E == Kc);
        __syncthreads();
    }
    // ---- refine level 4: bits [3:0] (exact key) ----
    if (!s_done) {
        if (tid < 256) hist2[tid] = 0;
        __syncthreads();
        for (int j = ALLOW_LO + tid; j <= ALLOW_HI; j += 1024) {
            unsigned u = fkey(rowl[j]);
            if ((u >> 4) == pref) atomicAdd(&hist2[u & 15], 1);
        }
        __syncthreads();
        suffix_select(hist2, Kc, &s_bucket, &s_above, &s_cntb, tid);
        __syncthreads();
        Kc -= s_above; E = s_cntb;
        tkey = (pref << 4) | (unsigned)s_bucket;   // exact 32-bit key of K-th largest
        if (E > Kc) {   // exact ties: find smallest jcut with count(key==tkey, j<=jcut) >= Kc
            if (tid == 0) { s_lo = ALLOW_LO; s_hi = ALLOW_HI; }
            __syncthreads();
            while (s_lo < s_hi) {
                int mid = (s_lo + s_hi) >> 1;
                if (tid == 0) s_tc = 0;
                __syncthreads();
                int loc = 0;
                for (int j = ALLOW_LO + tid; j <= mid; j += 1024)
                    if (fkey(rowl[j]) == tkey) loc++;
                if (loc) atomicAdd(&s_tc, loc);
                __syncthreads();
                if (tid == 0) { if (s_tc >= Kc) s_hi = mid; else s_lo = mid + 1; }
                __syncthreads();
            }
            jcut = s_lo;
        }
        __syncthreads();
    }

    // ---- compact kept set (ballot) + softmax weights ----
    float lsum = 0.f;
    for (int j = tid; j < KVLEN; j += 1024) {
        float s = rowl[j];
        bool keep;
        if (j < INIT_BUDGET || j >= RECENT_LO) keep = true;
        else {
            unsigned u = fkey(s);
            keep = (u > tkey) || (u == tkey && j <= jcut);
        }
        unsigned long long mask = __ballot(keep);
        if (mask) {
            int leader = (int)__ffsll((unsigned long long)mask) - 1;
            int cw = __popcll(mask);
            int base = 0;
            if (lane == leader) base = atomicAdd(&s_cnt, cw);
            base = __shfl(base, leader);
            if (keep) {
                int p = base + __popcll(mask & ((1ull << lane) - 1ull));
                float e = __expf(s - m);
                list[p] = j; wl[p] = e;
                lsum += e;
            }
        }
    }
    #pragma unroll
    for (int off = 32; off; off >>= 1) lsum += __shfl_xor(lsum, off);
    if (lane == 0) atomicAdd(&s_sum, lsum);
    __syncthreads();
    const int cnt = s_cnt;           // = 516
    const float inv = 1.0f / s_sum;

    // ---- gathered A@V: 32 groups x 32 lanes, 8 rows in flight ----
    const int G = tid >> 5, dq = tid & 31;
    const float4* vnew = (const float4*)(ws + OFF_V + (b * HKV + kv) * DD);
    const float* vbase = past_value + (size_t)(b * HKV + kv) * S_PAST * DD;
    float4 acc = {0.f, 0.f, 0.f, 0.f};
    for (int e = G; e < cnt; e += 256) {
        int jj[8]; float wv8[8]; float4 v4[8];
        #pragma unroll
        for (int k = 0; k < 8; ++k) {
            int ee = e + 32 * k;
            bool ok = ee < cnt;
            jj[k]  = ok ? list[ee] : 0;
            wv8[k] = ok ? wl[ee]   : 0.f;
        }
        #pragma unroll
        for (int k = 0; k < 8; ++k) {
            int j = jj[k];
            v4[k] = (j < S_PAST) ? ((const float4*)(vbase + (size_t)j * DD))[dq] : vnew[dq];
        }
        #pragma unroll
        for (int k = 0; k < 8; ++k) {
            acc.x = fmaf(wv8[k], v4[k].x, acc.x);
            acc.y = fmaf(wv8[k], v4[k].y, acc.y);
            acc.z = fmaf(wv8[k], v4[k].z, acc.z);
            acc.w = fmaf(wv8[k], v4[k].w, acc.w);
        }
    }
    red[G][dq * 4 + 0] = acc.x; red[G][dq * 4 + 1] = acc.y;
    red[G][dq * 4 + 2] = acc.z; red[G][dq * 4 + 3] = acc.w;
    __syncthreads();
    if (tid < DD) {
        float s = 0.f;
        #pragma unroll
        for (int gg = 0; gg < 32; ++gg) s += red[gg][tid];
        ws[OFF_A + b * HQ * DD + h * DD + tid] = s * inv;
    }
}

// ---------------- Kernel 5: output GEMV, 8-deep float4 pipeline ----------------
__global__ __launch_bounds__(256) void k_out(const float* __restrict__ ws,
                                             const float* __restrict__ wo,
                                             float* __restrict__ wsp) {
    __shared__ float a[BB][32];
    const int tid = threadIdx.x;
    const int bx = blockIdx.x, ch = blockIdx.y;
    const int i0 = ch * 32;
    if (tid < BB * 32) {
        int b = tid >> 5, ii = tid & 31;
        a[b][ii] = ws[OFF_A + b * HQ * DD + i0 + ii];
    }
    __syncthreads();
    const int c4 = bx * 1024 + tid * 4;
    const float* wp = wo + (size_t)i0 * HID + c4;
    float4 a0 = {0,0,0,0}, a1 = {0,0,0,0}, a2 = {0,0,0,0}, a3 = {0,0,0,0};
    for (int ii = 0; ii < 32; ii += 8) {
        float4 wr[8];
        #pragma unroll
        for (int u = 0; u < 8; ++u)
            wr[u] = ntload4((const float4*)(wp + (size_t)(ii + u) * HID));
        #pragma unroll
        for (int u = 0; u < 8; ++u) {
            float h0 = a[0][ii+u], h1 = a[1][ii+u], h2 = a[2][ii+u], h3 = a[3][ii+u];
            float4 w4 = wr[u];
            a0.x = fmaf(h0, w4.x, a0.x); a0.y = fmaf(h0, w4.y, a0.y); a0.z = fmaf(h0, w4.z, a0.z); a0.w = fmaf(h0, w4.w, a0.w);
            a1.x = fmaf(h1, w4.x, a1.x); a1.y = fmaf(h1, w4.y, a1.y); a1.z = fmaf(h1, w4.z, a1.z); a1.w = fmaf(h1, w4.w, a1.w);
            a2.x = fmaf(h2, w4.x, a2.x); a2.y = fmaf(h2, w4.y, a2.y); a2.z = fmaf(h2, w4.z, a2.z); a2.w = fmaf(h2, w4.w, a2.w);
            a3.x = fmaf(h3, w4.x, a3.x); a3.y = fmaf(h3, w4.y, a3.y); a3.z = fmaf(h3, w4.z, a3.z); a3.w = fmaf(h3, w4.w, a3.w);
        }
    }
    const int cq = bx * 256 + tid;
    ((float4*)(wsp + (size_t)(ch * 4 + 0) * HID))[cq] = a0;
    ((float4*)(wsp + (size_t)(ch * 4 + 1) * HID))[cq] = a1;
    ((float4*)(wsp + (size_t)(ch * 4 + 2) * HID))[cq] = a2;
    ((float4*)(wsp + (size_t)(ch * 4 + 3) * HID))[cq] = a3;
}

// ---------------- Kernel 6: reduce out partials -> d_out ----------------
__global__ __launch_bounds__(256) void k_out_red(const float* __restrict__ wsp,
                                                 float* __restrict__ out) {
    __shared__ float sh[2][BB][128];
    const int tid = threadIdx.x;
    const int i = tid & 127, half = tid >> 7;
    const int c = blockIdx.x * 128 + i;
    float s0 = 0.f, s1 = 0.f, s2 = 0.f, s3 = 0.f;
    for (int cb = 0; cb < 64; cb += 8) {
        float r[8][4];
        #pragma unroll
        for (int u = 0; u < 8; ++u) {
            const float* p = wsp + (size_t)((half * 64 + cb + u) * 4) * HID + c;
            r[u][0] = p[0]; r[u][1] = p[HID]; r[u][2] = p[2 * HID]; r[u][3] = p[3 * HID];
        }
        #pragma unroll
        for (int u = 0; u < 8; ++u) { s0 += r[u][0]; s1 += r[u][1]; s2 += r[u][2]; s3 += r[u][3]; }
    }
    sh[half][0][i] = s0; sh[half][1][i] = s1; sh[half][2][i] = s2; sh[half][3][i] = s3;
    __syncthreads();
    if (tid < 128) {
        #pragma unroll
        for (int b = 0; b < BB; ++b)
            out[b * HID + c] = sh[0][b][i] + sh[1][b][i];
    }
}

extern "C" void kernel_launch(void* const* d_in, const int* in_sizes, int n_in,
                              void* d_out, int out_size, void* d_ws, size_t ws_size,
                              hipStream_t stream) {
    const float* hidden = (const float*)d_in[0];
    const float* cosp   = (const float*)d_in[1];
    const float* sinp   = (const float*)d_in[2];
    const float* pk     = (const float*)d_in[3];
    const float* pv     = (const float*)d_in[4];
    const float* wq     = (const float*)d_in[5];
    const float* wk     = (const float*)d_in[6];
    const float* wv     = (const float*)d_in[7];
    const float* wo     = (const float*)d_in[8];
    float* out = (float*)d_out;
    float* ws  = (float*)d_ws;
    float* wsp = ws + OFF_P;

    k_qkv    <<<dim3(6, NCH1), 256,  0, stream>>>(hidden, wq, wk, wv, wsp);
    k_qkv_red<<<48,            256,  0, stream>>>(wsp, cosp, sinp, ws);
    k_scores <<<BB * HKV * 32, 256,  0, stream>>>(pk, ws);
    k_attn   <<<BB * HQ,       1024, 0, stream>>>(pv, ws);
    k_out    <<<dim3(4, NCH2), 256,  0, stream>>>(ws, wo, wsp);
    k_out_red<<<32,            256,  0, stream>>>(wsp, out);
}